// Round 1
// baseline (5340.678 us; speedup 1.0000x reference)
//
#include <hip/hip_runtime.h>

#define F_IN 1433
#define H1 200
#define H2 80
#define NC 7

// Generic fp32 tiled GEMM: C[M,N] = A[M,K] @ B[K,N] (+ bias per col if bias != nullptr)
// 64x64 tile, 256 threads, 4x4 per thread, BK=16.
__global__ void gemm_tiled(const float* __restrict__ A, const float* __restrict__ B,
                           const float* __restrict__ bias, float* __restrict__ C,
                           int M, int K, int N, int tilesN) {
    const int bx = blockIdx.x % tilesN;
    const int by = blockIdx.x / tilesN;
    const int tid = threadIdx.x;
    const int tx = tid & 15, ty = tid >> 4;
    __shared__ float As[64][17];  // +1 pad to dodge bank conflicts
    __shared__ float Bs[16][65];
    float acc[4][4] = {};
    const int row0 = by * 64, col0 = bx * 64;

    for (int k0 = 0; k0 < K; k0 += 16) {
        // Load A tile 64x16 (1024 elems / 256 threads = 4 each)
        #pragma unroll
        for (int l = 0; l < 4; ++l) {
            int e = tid + l * 256;
            int r = e >> 4, kk = e & 15;
            int gr = row0 + r, gk = k0 + kk;
            As[r][kk] = (gr < M && gk < K) ? A[(size_t)gr * K + gk] : 0.f;
        }
        // Load B tile 16x64
        #pragma unroll
        for (int l = 0; l < 4; ++l) {
            int e = tid + l * 256;
            int kk = e >> 6, c = e & 63;
            int gk = k0 + kk, gc = col0 + c;
            Bs[kk][c] = (gk < K && gc < N) ? B[(size_t)gk * N + gc] : 0.f;
        }
        __syncthreads();
        #pragma unroll
        for (int kk = 0; kk < 16; ++kk) {
            float a[4], b[4];
            #pragma unroll
            for (int i = 0; i < 4; ++i) a[i] = As[ty + 16 * i][kk];
            #pragma unroll
            for (int j = 0; j < 4; ++j) b[j] = Bs[kk][tx + 16 * j];
            #pragma unroll
            for (int i = 0; i < 4; ++i)
                #pragma unroll
                for (int j = 0; j < 4; ++j)
                    acc[i][j] += a[i] * b[j];
        }
        __syncthreads();
    }
    #pragma unroll
    for (int i = 0; i < 4; ++i) {
        int gr = row0 + ty + 16 * i;
        if (gr >= M) continue;
        #pragma unroll
        for (int j = 0; j < 4; ++j) {
            int gc = col0 + tx + 16 * j;
            if (gc >= N) continue;
            float v = acc[i][j];
            if (bias) v += bias[gc];
            C[(size_t)gr * N + gc] = v;
        }
    }
}

// agg[i*D + j] = bias[j]  (grid-stride over n = rows*D)
__global__ void init_bias_kernel(float* __restrict__ agg, const float* __restrict__ bias,
                                 long long n, int D) {
    long long i = (long long)blockIdx.x * blockDim.x + threadIdx.x;
    long long stride = (long long)gridDim.x * blockDim.x;
    for (; i < n; i += stride) {
        agg[i] = bias[(int)(i % D)];
    }
}

// For each edge e: agg[dst[e], :] += w[e] * h[src[e], :]   (64 lanes per edge)
template <int D>
__global__ void spmm_edges(const float* __restrict__ h, const int* __restrict__ src,
                           const int* __restrict__ dst, const float* __restrict__ w,
                           float* __restrict__ agg, int E) {
    const int epb = 4;  // blockDim 256 = 4 edges x 64 lanes
    int e = blockIdx.x * epb + (threadIdx.x >> 6);
    int lane = threadIdx.x & 63;
    if (e >= E) return;
    int s = src[e], d = dst[e];
    float wt = w[e];
    const float* hs = h + (size_t)s * D;
    float* ad = agg + (size_t)d * D;
    #pragma unroll
    for (int j = lane; j < D; j += 64) {
        atomicAdd(&ad[j], wt * hs[j]);
    }
}

__global__ void relu_kernel(float* __restrict__ x, long long n) {
    long long i = (long long)blockIdx.x * blockDim.x + threadIdx.x;
    long long stride = (long long)gridDim.x * blockDim.x;
    for (; i < n; i += stride) {
        float v = x[i];
        x[i] = v > 0.f ? v : 0.f;
    }
}

extern "C" void kernel_launch(void* const* d_in, const int* in_sizes, int n_in,
                              void* d_out, int out_size, void* d_ws, size_t ws_size,
                              hipStream_t stream) {
    const float* x        = (const float*)d_in[0];
    const int*   edge_src = (const int*)d_in[1];
    const int*   edge_dst = (const int*)d_in[2];
    const float* edge_w   = (const float*)d_in[3];
    const float* W1       = (const float*)d_in[4];
    const float* b1       = (const float*)d_in[5];
    const float* W2       = (const float*)d_in[6];
    const float* b2       = (const float*)d_in[7];
    const float* Wfc      = (const float*)d_in[8];
    const float* bfc      = (const float*)d_in[9];
    float* out = (float*)d_out;

    const int N = in_sizes[0] / F_IN;   // 100000
    const int E = in_sizes[1];          // 3200000

    // Workspace layout (fp32):
    //   [0, N*H1)        : h0 = x@W1, later reused as h2 = h1@W2 (N*H2 <= N*H1)
    //   [N*H1, 2*N*H1)   : agg1 (-> h1 after relu), later reused as agg2 (-> h3)
    float* h0   = (float*)d_ws;
    float* agg1 = h0 + (size_t)N * H1;
    float* h1   = agg1;
    float* h2   = h0;
    float* agg2 = agg1;
    float* h3   = agg2;

    // ---- Layer 1 ----
    {
        int tilesN = (H1 + 63) / 64;           // 4
        int tilesM = (N + 63) / 64;            // 1563
        gemm_tiled<<<tilesM * tilesN, 256, 0, stream>>>(x, W1, nullptr, h0, N, F_IN, H1, tilesN);
    }
    {
        long long n = (long long)N * H1;
        init_bias_kernel<<<2048, 256, 0, stream>>>(agg1, b1, n, H1);
    }
    spmm_edges<H1><<<(E + 3) / 4, 256, 0, stream>>>(h0, edge_src, edge_dst, edge_w, agg1, E);
    relu_kernel<<<2048, 256, 0, stream>>>(agg1, (long long)N * H1);

    // ---- Layer 2 ----
    {
        int tilesN = (H2 + 63) / 64;           // 2
        int tilesM = (N + 63) / 64;
        gemm_tiled<<<tilesM * tilesN, 256, 0, stream>>>(h1, W2, nullptr, h2, N, H1, H2, tilesN);
    }
    {
        long long n = (long long)N * H2;
        init_bias_kernel<<<2048, 256, 0, stream>>>(agg2, b2, n, H2);
    }
    spmm_edges<H2><<<(E + 3) / 4, 256, 0, stream>>>(h2, edge_src, edge_dst, edge_w, agg2, E);
    relu_kernel<<<2048, 256, 0, stream>>>(agg2, (long long)N * H2);

    // ---- FC ----
    {
        int tilesN = 1;                        // 7 cols
        int tilesM = (N + 63) / 64;
        gemm_tiled<<<tilesM * tilesN, 256, 0, stream>>>(h3, Wfc, bfc, out, N, H2, NC, tilesN);
    }
}

// Round 2
// 3097.102 us; speedup vs baseline: 1.7244x; 1.7244x over previous
//
#include <hip/hip_runtime.h>

#define F_IN 1433
#define H1 200
#define H2 80
#define NC 7

// ---------------- fp32 tiled GEMM (round-0, unchanged) ----------------
__global__ void gemm_tiled(const float* __restrict__ A, const float* __restrict__ B,
                           const float* __restrict__ bias, float* __restrict__ C,
                           int M, int K, int N, int tilesN) {
    const int bx = blockIdx.x % tilesN;
    const int by = blockIdx.x / tilesN;
    const int tid = threadIdx.x;
    const int tx = tid & 15, ty = tid >> 4;
    __shared__ float As[64][17];
    __shared__ float Bs[16][65];
    float acc[4][4] = {};
    const int row0 = by * 64, col0 = bx * 64;

    for (int k0 = 0; k0 < K; k0 += 16) {
        #pragma unroll
        for (int l = 0; l < 4; ++l) {
            int e = tid + l * 256;
            int r = e >> 4, kk = e & 15;
            int gr = row0 + r, gk = k0 + kk;
            As[r][kk] = (gr < M && gk < K) ? A[(size_t)gr * K + gk] : 0.f;
        }
        #pragma unroll
        for (int l = 0; l < 4; ++l) {
            int e = tid + l * 256;
            int kk = e >> 6, c = e & 63;
            int gk = k0 + kk, gc = col0 + c;
            Bs[kk][c] = (gk < K && gc < N) ? B[(size_t)gk * N + gc] : 0.f;
        }
        __syncthreads();
        #pragma unroll
        for (int kk = 0; kk < 16; ++kk) {
            float a[4], b[4];
            #pragma unroll
            for (int i = 0; i < 4; ++i) a[i] = As[ty + 16 * i][kk];
            #pragma unroll
            for (int j = 0; j < 4; ++j) b[j] = Bs[kk][tx + 16 * j];
            #pragma unroll
            for (int i = 0; i < 4; ++i)
                #pragma unroll
                for (int j = 0; j < 4; ++j)
                    acc[i][j] += a[i] * b[j];
        }
        __syncthreads();
    }
    #pragma unroll
    for (int i = 0; i < 4; ++i) {
        int gr = row0 + ty + 16 * i;
        if (gr >= M) continue;
        #pragma unroll
        for (int j = 0; j < 4; ++j) {
            int gc = col0 + tx + 16 * j;
            if (gc >= N) continue;
            float v = acc[i][j];
            if (bias) v += bias[gc];
            C[(size_t)gr * N + gc] = v;
        }
    }
}

// ---------------- CSR build ----------------
__global__ void zero_ints(int* __restrict__ p, int n) {
    int i = blockIdx.x * blockDim.x + threadIdx.x;
    int stride = gridDim.x * blockDim.x;
    for (; i < n; i += stride) p[i] = 0;
}

__global__ void hist_dst(const int* __restrict__ dst, int* __restrict__ counts, int E) {
    int i = blockIdx.x * blockDim.x + threadIdx.x;
    int stride = gridDim.x * blockDim.x;
    for (; i < E; i += stride) atomicAdd(&counts[dst[i]], 1);
}

// chunk = 2048 elements per block (256 thr x 8)
__global__ void chunk_sums(const int* __restrict__ counts, int* __restrict__ csum, int N) {
    __shared__ int s[256];
    int b = blockIdx.x, t = threadIdx.x;
    int base = b * 2048 + t * 8;
    int loc = 0;
    #pragma unroll
    for (int i = 0; i < 8; ++i) {
        int gi = base + i;
        if (gi < N) loc += counts[gi];
    }
    s[t] = loc;
    __syncthreads();
    for (int off = 128; off > 0; off >>= 1) {
        if (t < off) s[t] += s[t + off];
        __syncthreads();
    }
    if (t == 0) csum[b] = s[0];
}

__global__ void scan_chunks(const int* __restrict__ csum, int* __restrict__ cbase, int NB) {
    if (blockIdx.x == 0 && threadIdx.x == 0) {
        int run = 0;
        for (int b = 0; b < NB; ++b) { cbase[b] = run; run += csum[b]; }
    }
}

__global__ void scan_final(const int* __restrict__ counts, const int* __restrict__ cbase,
                           int* __restrict__ row_start, int* __restrict__ cursor, int N) {
    __shared__ int s[256];
    int b = blockIdx.x, t = threadIdx.x;
    int base = b * 2048 + t * 8;
    int loc = 0;
    #pragma unroll
    for (int i = 0; i < 8; ++i) {
        int gi = base + i;
        if (gi < N) loc += counts[gi];
    }
    s[t] = loc;
    __syncthreads();
    for (int off = 1; off < 256; off <<= 1) {
        int v = (t >= off) ? s[t - off] : 0;
        __syncthreads();
        s[t] += v;
        __syncthreads();
    }
    int run = cbase[b] + s[t] - loc;   // exclusive prefix for this thread
    for (int i = 0; i < 8; ++i) {
        int gi = base + i;
        if (gi < N) {
            row_start[gi] = run;
            cursor[gi] = run;
            run += counts[gi];
        }
    }
}

__global__ void scatter_edges(const int* __restrict__ src, const int* __restrict__ dst,
                              const float* __restrict__ w, int* __restrict__ cursor,
                              int2* __restrict__ csr, int E) {
    int i = blockIdx.x * blockDim.x + threadIdx.x;
    int stride = gridDim.x * blockDim.x;
    for (; i < E; i += stride) {
        int d = dst[i];
        int pos = atomicAdd(&cursor[d], 1);
        csr[pos] = make_int2(src[i], __float_as_int(w[i]));
    }
}

// ---------------- CSR SPMM: one wave per dst row, bias+relu fused ----------------
template <int D, bool RELU>
__global__ void spmm_csr(const float* __restrict__ h, const int2* __restrict__ csr,
                         const int* __restrict__ row_start, const int* __restrict__ counts,
                         const float* __restrict__ bias, float* __restrict__ out, int N) {
    int row = blockIdx.x * 4 + (threadIdx.x >> 6);
    int lane = threadIdx.x & 63;
    if (row >= N) return;
    int p = row_start[row], len = counts[row];
    constexpr int NK = (D + 63) / 64;
    float acc[NK];
    #pragma unroll
    for (int k = 0; k < NK; ++k) {
        int j = lane + 64 * k;
        acc[k] = (j < D) ? bias[j] : 0.f;
    }
    int2 ew = (len > 0) ? csr[p] : make_int2(0, 0);
    for (int q = 0; q < len; ++q) {
        int2 cur = ew;
        if (q + 1 < len) ew = csr[p + q + 1];   // prefetch next edge
        const float* hs = h + (size_t)cur.x * D;
        float wt = __int_as_float(cur.y);
        #pragma unroll
        for (int k = 0; k < NK; ++k) {
            int j = lane + 64 * k;
            if (j < D) acc[k] += wt * hs[j];
        }
    }
    #pragma unroll
    for (int k = 0; k < NK; ++k) {
        int j = lane + 64 * k;
        if (j < D) {
            float v = acc[k];
            if (RELU) v = v > 0.f ? v : 0.f;
            out[(size_t)row * D + j] = v;
        }
    }
}

// ---------------- round-0 fallback kernels (used only if ws too small) ----------------
__global__ void init_bias_kernel(float* __restrict__ agg, const float* __restrict__ bias,
                                 long long n, int D) {
    long long i = (long long)blockIdx.x * blockDim.x + threadIdx.x;
    long long stride = (long long)gridDim.x * blockDim.x;
    for (; i < n; i += stride) agg[i] = bias[(int)(i % D)];
}

template <int D>
__global__ void spmm_edges(const float* __restrict__ h, const int* __restrict__ src,
                           const int* __restrict__ dst, const float* __restrict__ w,
                           float* __restrict__ agg, int E) {
    int e = blockIdx.x * 4 + (threadIdx.x >> 6);
    int lane = threadIdx.x & 63;
    if (e >= E) return;
    int s = src[e], d = dst[e];
    float wt = w[e];
    const float* hs = h + (size_t)s * D;
    float* ad = agg + (size_t)d * D;
    for (int j = lane; j < D; j += 64) atomicAdd(&ad[j], wt * hs[j]);
}

__global__ void relu_kernel(float* __restrict__ x, long long n) {
    long long i = (long long)blockIdx.x * blockDim.x + threadIdx.x;
    long long stride = (long long)gridDim.x * blockDim.x;
    for (; i < n; i += stride) {
        float v = x[i];
        x[i] = v > 0.f ? v : 0.f;
    }
}

extern "C" void kernel_launch(void* const* d_in, const int* in_sizes, int n_in,
                              void* d_out, int out_size, void* d_ws, size_t ws_size,
                              hipStream_t stream) {
    const float* x        = (const float*)d_in[0];
    const int*   edge_src = (const int*)d_in[1];
    const int*   edge_dst = (const int*)d_in[2];
    const float* edge_w   = (const float*)d_in[3];
    const float* W1       = (const float*)d_in[4];
    const float* b1       = (const float*)d_in[5];
    const float* W2       = (const float*)d_in[6];
    const float* b2       = (const float*)d_in[7];
    const float* Wfc      = (const float*)d_in[8];
    const float* bfc      = (const float*)d_in[9];
    float* out = (float*)d_out;

    const int N = in_sizes[0] / F_IN;   // 100000
    const int E = in_sizes[1];          // 3200000
    const int NB = (N + 2047) / 2048;   // scan chunks

    // ---- workspace layout ----
    float* h0  = (float*)d_ws;                       // N*H1 floats
    float* agg = h0 + (size_t)N * H1;                // N*H1 floats
    int* counts    = (int*)(agg + (size_t)N * H1);   // N
    int* row_start = counts + N;                     // N
    int* cursor    = row_start + N;                  // N
    int* csum      = cursor + N;                     // NB
    int* cbase     = csum + NB;                      // NB
    size_t csr_off = (size_t)(cbase + NB) - (size_t)d_ws;
    csr_off = (csr_off + 15) & ~(size_t)15;
    int2* csr = (int2*)((char*)d_ws + csr_off);      // E int2
    size_t needed = csr_off + (size_t)E * sizeof(int2);

    float* h1 = agg;   // layer-1 output (after fused bias+relu)
    float* h2 = h0;    // layer-2 gemm output
    float* h3 = agg;   // layer-2 aggregated output

    const int tilesM = (N + 63) / 64;

    if (ws_size >= needed) {
        // ---- CSR build (once; reused by both layers) ----
        zero_ints<<<256, 256, 0, stream>>>(counts, N);
        hist_dst<<<2048, 256, 0, stream>>>(edge_dst, counts, E);
        chunk_sums<<<NB, 256, 0, stream>>>(counts, csum, N);
        scan_chunks<<<1, 64, 0, stream>>>(csum, cbase, NB);
        scan_final<<<NB, 256, 0, stream>>>(counts, cbase, row_start, cursor, N);
        scatter_edges<<<2048, 256, 0, stream>>>(edge_src, edge_dst, edge_w, cursor, csr, E);

        // ---- Layer 1 ----
        gemm_tiled<<<tilesM * 4, 256, 0, stream>>>(x, W1, nullptr, h0, N, F_IN, H1, 4);
        spmm_csr<H1, true><<<(N + 3) / 4, 256, 0, stream>>>(h0, csr, row_start, counts, b1, h1, N);

        // ---- Layer 2 ----
        gemm_tiled<<<tilesM * 2, 256, 0, stream>>>(h1, W2, nullptr, h2, N, H1, H2, 2);
        spmm_csr<H2, true><<<(N + 3) / 4, 256, 0, stream>>>(h2, csr, row_start, counts, b2, h3, N);

        // ---- FC ----
        gemm_tiled<<<tilesM, 256, 0, stream>>>(h3, Wfc, bfc, out, N, H2, NC, 1);
    } else {
        // ---- fallback: round-0 atomic path ----
        gemm_tiled<<<tilesM * 4, 256, 0, stream>>>(x, W1, nullptr, h0, N, F_IN, H1, 4);
        init_bias_kernel<<<2048, 256, 0, stream>>>(agg, b1, (long long)N * H1, H1);
        spmm_edges<H1><<<(E + 3) / 4, 256, 0, stream>>>(h0, edge_src, edge_dst, edge_w, agg, E);
        relu_kernel<<<2048, 256, 0, stream>>>(agg, (long long)N * H1);
        gemm_tiled<<<tilesM * 2, 256, 0, stream>>>(h1, W2, nullptr, h2, N, H1, H2, 2);
        init_bias_kernel<<<2048, 256, 0, stream>>>(agg, b2, (long long)N * H2, H2);
        spmm_edges<H2><<<(E + 3) / 4, 256, 0, stream>>>(h2, edge_src, edge_dst, edge_w, agg, E);
        relu_kernel<<<2048, 256, 0, stream>>>(agg, (long long)N * H2);
        gemm_tiled<<<tilesM, 256, 0, stream>>>(h3, Wfc, bfc, out, N, H2, NC, 1);
    }
}

// Round 3
// 1836.725 us; speedup vs baseline: 2.9077x; 1.6862x over previous
//
#include <hip/hip_runtime.h>

#define F_IN 1433
#define H1 200
#define H2 80
#define NC 7

typedef __bf16 bf16x8 __attribute__((ext_vector_type(8)));
typedef float f32x4 __attribute__((ext_vector_type(4)));
typedef unsigned short u16x8 __attribute__((ext_vector_type(8)));

__device__ __forceinline__ unsigned short bf16_bits(__bf16 h) {
    union { __bf16 h; unsigned short u; } c; c.h = h; return c.u;
}
__device__ __forceinline__ void split_bf16(float a, __bf16& hi, __bf16& lo) {
    hi = (__bf16)a;
    lo = (__bf16)(a - (float)hi);
}

// =================== split-bf16 MFMA GEMM ===================
// C[M][NREAL] = A[M][K] @ B[K][NREAL] (+bias). B pre-converted to hi/lo bf16
// fragment-order planes: Bpre[hl][k8][col][j] (K padded to KSTEPS*32, cols to COLS).
// Block: 256 thr = 4 waves; BM=128 (wave w owns rows w*32..w*32+31); BN = COLS.
#define ASTRIDE 1032   // k8-plane stride in shorts: 128*8 + 8 pad (conflict-free writes, 16B-aligned reads)

template <int K, int KSTEPS, int COLS, int NT, bool BIAS>
__global__ __launch_bounds__(256, 2)
void gemm_mfma_split(const float* __restrict__ A, const unsigned short* __restrict__ Bpre,
                     const float* __restrict__ bias, float* __restrict__ C,
                     int M, int NREAL) {
    __shared__ alignas(16) unsigned short As[2 * 4 * ASTRIDE];   // [hl][k8l(stride ASTRIDE)][row][j]
    __shared__ alignas(16) unsigned short Bs[2 * 4 * COLS * 8];  // [hl][k8l][col][j]
    const int tid = threadIdx.x;
    const int wave = tid >> 6, lane = tid & 63;
    const int l15 = lane & 15, l4 = lane >> 4;
    const int row0 = blockIdx.x * 128;
    const int wrow0 = wave * 32;
    constexpr int planeB = KSTEPS * 4 * COLS * 8;  // shorts per hl plane in Bpre
    constexpr int ALO = 4 * ASTRIDE;               // lo-plane offset in As (shorts)
    constexpr int BLO = 4 * COLS * 8;              // lo-plane offset in Bs (shorts)

    f32x4 acc[2][NT];
    #pragma unroll
    for (int m = 0; m < 2; ++m)
        #pragma unroll
        for (int n = 0; n < NT; ++n) acc[m][n] = (f32x4){0.f, 0.f, 0.f, 0.f};

    for (int s = 0; s < KSTEPS; ++s) {
        const int k0 = s * 32;
        // ---- stage B chunk (pure 16B-chunk copy, already fragment-ordered) ----
        {
            constexpr int CH = 4 * COLS;  // 16B chunks per plane
            const u16x8* gHi = (const u16x8*)(Bpre + (size_t)s * 4 * COLS * 8);
            const u16x8* gLo = (const u16x8*)(Bpre + planeB + (size_t)s * 4 * COLS * 8);
            u16x8* lHi = (u16x8*)&Bs[0];
            u16x8* lLo = (u16x8*)&Bs[BLO];
            for (int i = tid; i < CH; i += 256) lHi[i] = gHi[i];
            for (int i = tid; i < CH; i += 256) lLo[i] = gLo[i];
        }
        // ---- stage A tile 128x32 fp32 -> hi/lo bf16 fragment-order ----
        #pragma unroll
        for (int i = 0; i < 8; ++i) {
            int q = tid + 256 * i;        // pair id in [0,2048)
            int row = q >> 4, c = q & 15; // k-pair index
            int gr = row0 + row;
            int k = k0 + 2 * c;
            float a0 = 0.f, a1 = 0.f;
            if (gr < M) {
                const float* ap = A + (size_t)gr * K + k;
                if (k < K) a0 = ap[0];
                if (k + 1 < K) a1 = ap[1];
            }
            __bf16 h0, l0, h1, l1;
            split_bf16(a0, h0, l0);
            split_bf16(a1, h1, l1);
            int k8l = c >> 2, j = (2 * c) & 7;
            int base = k8l * ASTRIDE + row * 8 + j;
            *(unsigned int*)&As[base] = (unsigned int)bf16_bits(h0) | ((unsigned int)bf16_bits(h1) << 16);
            *(unsigned int*)&As[ALO + base] = (unsigned int)bf16_bits(l0) | ((unsigned int)bf16_bits(l1) << 16);
        }
        __syncthreads();
        // ---- fragments + MFMA ----
        bf16x8 aHi[2], aLo[2];
        #pragma unroll
        for (int m = 0; m < 2; ++m) {
            int arow = wrow0 + m * 16 + l15;
            aHi[m] = *(const bf16x8*)&As[l4 * ASTRIDE + arow * 8];
            aLo[m] = *(const bf16x8*)&As[ALO + l4 * ASTRIDE + arow * 8];
        }
        #pragma unroll
        for (int n = 0; n < NT; ++n) {
            int bcol = n * 16 + l15;
            bf16x8 bHi = *(const bf16x8*)&Bs[(l4 * COLS + bcol) * 8];
            bf16x8 bLo = *(const bf16x8*)&Bs[BLO + (l4 * COLS + bcol) * 8];
            #pragma unroll
            for (int m = 0; m < 2; ++m) {
                acc[m][n] = __builtin_amdgcn_mfma_f32_16x16x32_bf16(aHi[m], bHi, acc[m][n], 0, 0, 0);
                acc[m][n] = __builtin_amdgcn_mfma_f32_16x16x32_bf16(aLo[m], bHi, acc[m][n], 0, 0, 0);
                acc[m][n] = __builtin_amdgcn_mfma_f32_16x16x32_bf16(aHi[m], bLo, acc[m][n], 0, 0, 0);
            }
        }
        __syncthreads();
    }
    // ---- epilogue: C/D layout col=lane&15, row=(lane>>4)*4+reg ----
    #pragma unroll
    for (int m = 0; m < 2; ++m) {
        int rbase = row0 + wrow0 + m * 16 + l4 * 4;
        #pragma unroll
        for (int n = 0; n < NT; ++n) {
            int col = n * 16 + l15;
            if (col >= NREAL) continue;
            float bv = BIAS ? bias[col] : 0.f;
            #pragma unroll
            for (int r = 0; r < 4; ++r) {
                int gr = rbase + r;
                if (gr < M) C[(size_t)gr * NREAL + col] = acc[m][n][r] + bv;
            }
        }
    }
}

// Convert W[K][NREAL] fp32 -> Bpre[hl][k8][col][j] bf16 hi/lo planes (zero-padded).
__global__ void convert_B(const float* __restrict__ W, unsigned short* __restrict__ out,
                          int K, int NREAL, int K8P, int COLS) {
    int plane = K8P * COLS * 8;
    int i = blockIdx.x * blockDim.x + threadIdx.x;
    int stride = gridDim.x * blockDim.x;
    for (; i < plane; i += stride) {
        int k8 = i / (COLS * 8);
        int rem = i % (COLS * 8);
        int col = rem >> 3, j = rem & 7;
        int k = k8 * 8 + j;
        float v = (k < K && col < NREAL) ? W[(size_t)k * NREAL + col] : 0.f;
        __bf16 hi, lo;
        split_bf16(v, hi, lo);
        out[i] = bf16_bits(hi);
        out[plane + i] = bf16_bits(lo);
    }
}

// =================== fp32 tiled GEMM (fallback path only) ===================
__global__ void gemm_tiled(const float* __restrict__ A, const float* __restrict__ B,
                           const float* __restrict__ bias, float* __restrict__ C,
                           int M, int K, int N, int tilesN) {
    const int bx = blockIdx.x % tilesN;
    const int by = blockIdx.x / tilesN;
    const int tid = threadIdx.x;
    const int tx = tid & 15, ty = tid >> 4;
    __shared__ float Asf[64][17];
    __shared__ float Bsf[16][65];
    float acc[4][4] = {};
    const int row0 = by * 64, col0 = bx * 64;
    for (int k0 = 0; k0 < K; k0 += 16) {
        #pragma unroll
        for (int l = 0; l < 4; ++l) {
            int e = tid + l * 256;
            int r = e >> 4, kk = e & 15;
            int gr = row0 + r, gk = k0 + kk;
            Asf[r][kk] = (gr < M && gk < K) ? A[(size_t)gr * K + gk] : 0.f;
        }
        #pragma unroll
        for (int l = 0; l < 4; ++l) {
            int e = tid + l * 256;
            int kk = e >> 6, c = e & 63;
            int gk = k0 + kk, gc = col0 + c;
            Bsf[kk][c] = (gk < K && gc < N) ? B[(size_t)gk * N + gc] : 0.f;
        }
        __syncthreads();
        #pragma unroll
        for (int kk = 0; kk < 16; ++kk) {
            float a[4], b[4];
            #pragma unroll
            for (int i = 0; i < 4; ++i) a[i] = Asf[ty + 16 * i][kk];
            #pragma unroll
            for (int j = 0; j < 4; ++j) b[j] = Bsf[kk][tx + 16 * j];
            #pragma unroll
            for (int i = 0; i < 4; ++i)
                #pragma unroll
                for (int j = 0; j < 4; ++j) acc[i][j] += a[i] * b[j];
        }
        __syncthreads();
    }
    #pragma unroll
    for (int i = 0; i < 4; ++i) {
        int gr = row0 + ty + 16 * i;
        if (gr >= M) continue;
        #pragma unroll
        for (int j = 0; j < 4; ++j) {
            int gc = col0 + tx + 16 * j;
            if (gc >= N) continue;
            float v = acc[i][j];
            if (bias) v += bias[gc];
            C[(size_t)gr * N + gc] = v;
        }
    }
}

// =================== CSR build ===================
__global__ void zero_ints(int* __restrict__ p, int n) {
    int i = blockIdx.x * blockDim.x + threadIdx.x;
    int stride = gridDim.x * blockDim.x;
    for (; i < n; i += stride) p[i] = 0;
}

__global__ void hist_dst(const int* __restrict__ dst, int* __restrict__ counts, int E) {
    int i = blockIdx.x * blockDim.x + threadIdx.x;
    int stride = gridDim.x * blockDim.x;
    for (; i < E; i += stride) atomicAdd(&counts[dst[i]], 1);
}

__global__ void chunk_sums(const int* __restrict__ counts, int* __restrict__ csum, int N) {
    __shared__ int s[256];
    int b = blockIdx.x, t = threadIdx.x;
    int base = b * 2048 + t * 8;
    int loc = 0;
    #pragma unroll
    for (int i = 0; i < 8; ++i) {
        int gi = base + i;
        if (gi < N) loc += counts[gi];
    }
    s[t] = loc;
    __syncthreads();
    for (int off = 128; off > 0; off >>= 1) {
        if (t < off) s[t] += s[t + off];
        __syncthreads();
    }
    if (t == 0) csum[b] = s[0];
}

__global__ void scan_chunks(const int* __restrict__ csum, int* __restrict__ cbase, int NB) {
    if (blockIdx.x == 0 && threadIdx.x == 0) {
        int run = 0;
        for (int b = 0; b < NB; ++b) { cbase[b] = run; run += csum[b]; }
    }
}

__global__ void scan_final(const int* __restrict__ counts, const int* __restrict__ cbase,
                           int* __restrict__ row_start, int* __restrict__ cursor, int N) {
    __shared__ int s[256];
    int b = blockIdx.x, t = threadIdx.x;
    int base = b * 2048 + t * 8;
    int loc = 0;
    #pragma unroll
    for (int i = 0; i < 8; ++i) {
        int gi = base + i;
        if (gi < N) loc += counts[gi];
    }
    s[t] = loc;
    __syncthreads();
    for (int off = 1; off < 256; off <<= 1) {
        int v = (t >= off) ? s[t - off] : 0;
        __syncthreads();
        s[t] += v;
        __syncthreads();
    }
    int run = cbase[b] + s[t] - loc;
    for (int i = 0; i < 8; ++i) {
        int gi = base + i;
        if (gi < N) {
            row_start[gi] = run;
            cursor[gi] = run;
            run += counts[gi];
        }
    }
}

__global__ void scatter_edges(const int* __restrict__ src, const int* __restrict__ dst,
                              const float* __restrict__ w, int* __restrict__ cursor,
                              int2* __restrict__ csr, int E) {
    int i = blockIdx.x * blockDim.x + threadIdx.x;
    int stride = gridDim.x * blockDim.x;
    for (; i < E; i += stride) {
        int d = dst[i];
        int pos = atomicAdd(&cursor[d], 1);
        csr[pos] = make_int2(src[i], __float_as_int(w[i]));
    }
}

// =================== CSR SPMM (one wave per row, bias+relu fused) ===================
template <int D, bool RELU>
__global__ void spmm_csr(const float* __restrict__ h, const int2* __restrict__ csr,
                         const int* __restrict__ row_start, const int* __restrict__ counts,
                         const float* __restrict__ bias, float* __restrict__ out, int N) {
    int row = blockIdx.x * 4 + (threadIdx.x >> 6);
    int lane = threadIdx.x & 63;
    if (row >= N) return;
    int p = row_start[row], len = counts[row];
    constexpr int NK = (D + 63) / 64;
    float acc[NK];
    #pragma unroll
    for (int k = 0; k < NK; ++k) {
        int j = lane + 64 * k;
        acc[k] = (j < D) ? bias[j] : 0.f;
    }
    int2 ew = (len > 0) ? csr[p] : make_int2(0, 0);
    for (int q = 0; q < len; ++q) {
        int2 cur = ew;
        if (q + 1 < len) ew = csr[p + q + 1];
        const float* hs = h + (size_t)cur.x * D;
        float wt = __int_as_float(cur.y);
        #pragma unroll
        for (int k = 0; k < NK; ++k) {
            int j = lane + 64 * k;
            if (j < D) acc[k] += wt * hs[j];
        }
    }
    #pragma unroll
    for (int k = 0; k < NK; ++k) {
        int j = lane + 64 * k;
        if (j < D) {
            float v = acc[k];
            if (RELU) v = v > 0.f ? v : 0.f;
            out[(size_t)row * D + j] = v;
        }
    }
}

// =================== fallback SPMM (atomic) ===================
__global__ void init_bias_kernel(float* __restrict__ agg, const float* __restrict__ bias,
                                 long long n, int D) {
    long long i = (long long)blockIdx.x * blockDim.x + threadIdx.x;
    long long stride = (long long)gridDim.x * blockDim.x;
    for (; i < n; i += stride) agg[i] = bias[(int)(i % D)];
}

template <int D>
__global__ void spmm_edges(const float* __restrict__ h, const int* __restrict__ src,
                           const int* __restrict__ dst, const float* __restrict__ w,
                           float* __restrict__ agg, int E) {
    int e = blockIdx.x * 4 + (threadIdx.x >> 6);
    int lane = threadIdx.x & 63;
    if (e >= E) return;
    int s = src[e], d = dst[e];
    float wt = w[e];
    const float* hs = h + (size_t)s * D;
    float* ad = agg + (size_t)d * D;
    for (int j = lane; j < D; j += 64) atomicAdd(&ad[j], wt * hs[j]);
}

__global__ void relu_kernel(float* __restrict__ x, long long n) {
    long long i = (long long)blockIdx.x * blockDim.x + threadIdx.x;
    long long stride = (long long)gridDim.x * blockDim.x;
    for (; i < n; i += stride) {
        float v = x[i];
        x[i] = v > 0.f ? v : 0.f;
    }
}

extern "C" void kernel_launch(void* const* d_in, const int* in_sizes, int n_in,
                              void* d_out, int out_size, void* d_ws, size_t ws_size,
                              hipStream_t stream) {
    const float* x        = (const float*)d_in[0];
    const int*   edge_src = (const int*)d_in[1];
    const int*   edge_dst = (const int*)d_in[2];
    const float* edge_w   = (const float*)d_in[3];
    const float* W1       = (const float*)d_in[4];
    const float* b1       = (const float*)d_in[5];
    const float* W2       = (const float*)d_in[6];
    const float* b2       = (const float*)d_in[7];
    const float* Wfc      = (const float*)d_in[8];
    const float* bfc      = (const float*)d_in[9];
    float* out = (float*)d_out;

    const int N = in_sizes[0] / F_IN;   // 100000
    const int E = in_sizes[1];          // 3200000
    const int NB = (N + 2047) / 2048;

    // ---- workspace layout ----
    float* h0  = (float*)d_ws;                       // N*H1
    float* agg = h0 + (size_t)N * H1;                // N*H1
    int* counts    = (int*)(agg + (size_t)N * H1);   // N
    int* row_start = counts + N;                     // N
    int* cursor    = row_start + N;                  // N
    int* csum      = cursor + N;                     // NB
    int* cbase     = csum + NB;                      // NB
    size_t csr_off = (size_t)(cbase + NB) - (size_t)d_ws;
    csr_off = (csr_off + 15) & ~(size_t)15;
    int2* csr = (int2*)((char*)d_ws + csr_off);      // E int2
    size_t boff = csr_off + (size_t)E * sizeof(int2);
    boff = (boff + 15) & ~(size_t)15;
    // GEMM1: K=1433 -> KSTEPS=45, K8P=180; COLS=208 (13 tiles)
    // GEMM2: K=200  -> KSTEPS=7,  K8P=28;  COLS=80  (5 tiles)
    // FC   : K=80   -> KSTEPS=3,  K8P=12;  COLS=16  (1 tile)
    const size_t B1n = 2ull * 180 * 208 * 8;
    const size_t B2n = 2ull * 28 * 80 * 8;
    const size_t Bfn = 2ull * 12 * 16 * 8;
    unsigned short* B1p = (unsigned short*)((char*)d_ws + boff);
    unsigned short* B2p = B1p + B1n;
    unsigned short* Bfp = B2p + B2n;
    size_t needed = boff + (B1n + B2n + Bfn) * sizeof(unsigned short);

    float* h1 = agg;
    float* h2 = h0;
    float* h3 = agg;

    const int MB = (N + 127) / 128;

    if (ws_size >= needed) {
        // ---- weight pre-convert (hi/lo bf16, fragment order) ----
        convert_B<<<(180 * 208 * 8 + 255) / 256, 256, 0, stream>>>(W1, B1p, F_IN, H1, 180, 208);
        convert_B<<<(28 * 80 * 8 + 255) / 256, 256, 0, stream>>>(W2, B2p, H1, H2, 28, 80);
        convert_B<<<(12 * 16 * 8 + 255) / 256, 256, 0, stream>>>(Wfc, Bfp, H2, NC, 12, 16);

        // ---- CSR build ----
        zero_ints<<<256, 256, 0, stream>>>(counts, N);
        hist_dst<<<2048, 256, 0, stream>>>(edge_dst, counts, E);
        chunk_sums<<<NB, 256, 0, stream>>>(counts, csum, N);
        scan_chunks<<<1, 64, 0, stream>>>(csum, cbase, NB);
        scan_final<<<NB, 256, 0, stream>>>(counts, cbase, row_start, cursor, N);
        scatter_edges<<<2048, 256, 0, stream>>>(edge_src, edge_dst, edge_w, cursor, csr, E);

        // ---- Layer 1 ----
        gemm_mfma_split<F_IN, 45, 208, 13, false><<<MB, 256, 0, stream>>>(x, B1p, nullptr, h0, N, H1);
        spmm_csr<H1, true><<<(N + 3) / 4, 256, 0, stream>>>(h0, csr, row_start, counts, b1, h1, N);

        // ---- Layer 2 ----
        gemm_mfma_split<H1, 7, 80, 5, false><<<MB, 256, 0, stream>>>(h1, B2p, nullptr, h2, N, H2);
        spmm_csr<H2, true><<<(N + 3) / 4, 256, 0, stream>>>(h2, csr, row_start, counts, b2, h3, N);

        // ---- FC ----
        gemm_mfma_split<H2, 3, 16, 1, true><<<MB, 256, 0, stream>>>(h3, Bfp, bfc, out, N, NC);
    } else {
        // ---- fallback: fp32 everything, atomic SPMM ----
        const int tilesM = (N + 63) / 64;
        gemm_tiled<<<tilesM * 4, 256, 0, stream>>>(x, W1, nullptr, h0, N, F_IN, H1, 4);
        init_bias_kernel<<<2048, 256, 0, stream>>>(agg, b1, (long long)N * H1, H1);
        spmm_edges<H1><<<(E + 3) / 4, 256, 0, stream>>>(h0, edge_src, edge_dst, edge_w, agg, E);
        relu_kernel<<<2048, 256, 0, stream>>>(agg, (long long)N * H1);
        gemm_tiled<<<tilesM * 2, 256, 0, stream>>>(h1, W2, nullptr, h2, N, H1, H2, 2);
        init_bias_kernel<<<2048, 256, 0, stream>>>(agg, b2, (long long)N * H2, H2);
        spmm_edges<H2><<<(E + 3) / 4, 256, 0, stream>>>(h2, edge_src, edge_dst, edge_w, agg, E);
        relu_kernel<<<2048, 256, 0, stream>>>(agg, (long long)N * H2);
        gemm_tiled<<<tilesM, 256, 0, stream>>>(h3, Wfc, bfc, out, N, H2, NC, 1);
    }
}

// Round 4
// 1595.782 us; speedup vs baseline: 3.3467x; 1.1510x over previous
//
#include <hip/hip_runtime.h>

#define F_IN 1433
#define H1 200
#define H2 80
#define NC 7

typedef __bf16 bf16x8 __attribute__((ext_vector_type(8)));
typedef float f32x4 __attribute__((ext_vector_type(4)));
typedef unsigned short u16x8 __attribute__((ext_vector_type(8)));

__device__ __forceinline__ unsigned short bf16_bits(__bf16 h) {
    union { __bf16 h; unsigned short u; } c; c.h = h; return c.u;
}
__device__ __forceinline__ void split_bf16(float a, __bf16& hi, __bf16& lo) {
    hi = (__bf16)a;
    lo = (__bf16)(a - (float)hi);
}

// =================== LDS-free split-bf16 MFMA GEMM ===================
// C[M][NREAL] = A[M][K] @ B[K][NREAL] (+bias). B pre-converted to hi/lo bf16
// fragment-order planes: Bpre[hl][k8][col][j]. No LDS, no barriers:
// A fragments loaded per-lane direct from global (row l&15, k-slice l>>4),
// converted to hi/lo bf16 in registers; B fragments read as coalesced 16B
// chunks from L2-resident Bpre. A(s+1) prefetch overlaps MFMA(s).
// Block: 256 thr = 4 waves; BM=128 (wave w owns rows w*32..w*32+31).
template <int K, int KSTEPS, int COLS, int NT, bool BIAS, bool A16>
__global__ __launch_bounds__(256, 2)
void gemm_mfma_direct(const float* __restrict__ A, const unsigned short* __restrict__ Bpre,
                      const float* __restrict__ bias, float* __restrict__ C,
                      int M, int NREAL) {
    const int tid = threadIdx.x;
    const int wave = tid >> 6, lane = tid & 63;
    const int l15 = lane & 15, l4 = lane >> 4;
    const int row0 = blockIdx.x * 128 + wave * 32;
    constexpr int planeChunks = KSTEPS * 4 * COLS;   // 16B chunks per hl plane
    constexpr bool PART = (KSTEPS * 32 > K);         // last k-step partially OOB
    const u16x8* Bv = (const u16x8*)Bpre;

    f32x4 acc[2][NT];
    #pragma unroll
    for (int m = 0; m < 2; ++m)
        #pragma unroll
        for (int n = 0; n < NT; ++n) acc[m][n] = (f32x4){0.f, 0.f, 0.f, 0.f};

    // A row base pointers for the two m-frags (clamped; OOB rows masked at store)
    int r0 = row0 + l15;      if (r0 >= M) r0 = M - 1;
    int r1 = row0 + 16 + l15; if (r1 >= M) r1 = M - 1;
    const float* arow0 = A + (size_t)r0 * K;
    const float* arow1 = A + (size_t)r1 * K;

    float af[2][8];

    auto loadA = [&](int s) {
        const int kb = s * 32 + l4 * 8;
        const float* ar[2] = {arow0, arow1};
        #pragma unroll
        for (int m = 0; m < 2; ++m) {
            if (PART && s == KSTEPS - 1) {
                #pragma unroll
                for (int j = 0; j < 8; ++j)
                    af[m][j] = (kb + j < K) ? ar[m][kb + j] : 0.f;
            } else if (A16) {
                f32x4 u = *(const f32x4*)(ar[m] + kb);
                f32x4 v = *(const f32x4*)(ar[m] + kb + 4);
                #pragma unroll
                for (int j = 0; j < 4; ++j) { af[m][j] = u[j]; af[m][4 + j] = v[j]; }
            } else {
                #pragma unroll
                for (int j = 0; j < 8; ++j) af[m][j] = ar[m][kb + j];
            }
        }
    };

    loadA(0);
    for (int s = 0; s < KSTEPS; ++s) {
        // convert current step's A floats -> hi/lo bf16 fragments
        bf16x8 aHi[2], aLo[2];
        #pragma unroll
        for (int m = 0; m < 2; ++m)
            #pragma unroll
            for (int j = 0; j < 8; ++j) {
                __bf16 hi, lo;
                split_bf16(af[m][j], hi, lo);
                aHi[m][j] = hi;
                aLo[m][j] = lo;
            }
        // prefetch next step's A floats (latency hidden under MFMAs below)
        if (s + 1 < KSTEPS) loadA(s + 1);

        const u16x8* bh = Bv + (size_t)(s * 4 + l4) * COLS + l15;
        #pragma unroll
        for (int n = 0; n < NT; ++n) {
            bf16x8 bHi = *(const bf16x8*)(bh + n * 16);
            bf16x8 bLo = *(const bf16x8*)(bh + planeChunks + n * 16);
            #pragma unroll
            for (int m = 0; m < 2; ++m) {
                acc[m][n] = __builtin_amdgcn_mfma_f32_16x16x32_bf16(aHi[m], bHi, acc[m][n], 0, 0, 0);
                acc[m][n] = __builtin_amdgcn_mfma_f32_16x16x32_bf16(aLo[m], bHi, acc[m][n], 0, 0, 0);
                acc[m][n] = __builtin_amdgcn_mfma_f32_16x16x32_bf16(aHi[m], bLo, acc[m][n], 0, 0, 0);
            }
        }
    }

    // epilogue: C/D layout col=lane&15, row=(lane>>4)*4+reg
    #pragma unroll
    for (int m = 0; m < 2; ++m) {
        int rbase = row0 + m * 16 + l4 * 4;
        #pragma unroll
        for (int n = 0; n < NT; ++n) {
            int col = n * 16 + l15;
            if (col >= NREAL) continue;
            float bv = BIAS ? bias[col] : 0.f;
            #pragma unroll
            for (int r = 0; r < 4; ++r) {
                int gr = rbase + r;
                if (gr < M) C[(size_t)gr * NREAL + col] = acc[m][n][r] + bv;
            }
        }
    }
}

// Convert W[K][NREAL] fp32 -> Bpre[hl][k8][col][j] bf16 hi/lo planes (zero-padded).
__global__ void convert_B(const float* __restrict__ W, unsigned short* __restrict__ out,
                          int K, int NREAL, int K8P, int COLS) {
    int plane = K8P * COLS * 8;
    int i = blockIdx.x * blockDim.x + threadIdx.x;
    int stride = gridDim.x * blockDim.x;
    for (; i < plane; i += stride) {
        int k8 = i / (COLS * 8);
        int rem = i % (COLS * 8);
        int col = rem >> 3, j = rem & 7;
        int k = k8 * 8 + j;
        float v = (k < K && col < NREAL) ? W[(size_t)k * NREAL + col] : 0.f;
        __bf16 hi, lo;
        split_bf16(v, hi, lo);
        out[i] = bf16_bits(hi);
        out[plane + i] = bf16_bits(lo);
    }
}

// =================== fp32 tiled GEMM (fallback path only) ===================
__global__ void gemm_tiled(const float* __restrict__ A, const float* __restrict__ B,
                           const float* __restrict__ bias, float* __restrict__ C,
                           int M, int K, int N, int tilesN) {
    const int bx = blockIdx.x % tilesN;
    const int by = blockIdx.x / tilesN;
    const int tid = threadIdx.x;
    const int tx = tid & 15, ty = tid >> 4;
    __shared__ float Asf[64][17];
    __shared__ float Bsf[16][65];
    float acc[4][4] = {};
    const int row0 = by * 64, col0 = bx * 64;
    for (int k0 = 0; k0 < K; k0 += 16) {
        #pragma unroll
        for (int l = 0; l < 4; ++l) {
            int e = tid + l * 256;
            int r = e >> 4, kk = e & 15;
            int gr = row0 + r, gk = k0 + kk;
            Asf[r][kk] = (gr < M && gk < K) ? A[(size_t)gr * K + gk] : 0.f;
        }
        #pragma unroll
        for (int l = 0; l < 4; ++l) {
            int e = tid + l * 256;
            int kk = e >> 6, c = e & 63;
            int gk = k0 + kk, gc = col0 + c;
            Bsf[kk][c] = (gk < K && gc < N) ? B[(size_t)gk * N + gc] : 0.f;
        }
        __syncthreads();
        #pragma unroll
        for (int kk = 0; kk < 16; ++kk) {
            float a[4], b[4];
            #pragma unroll
            for (int i = 0; i < 4; ++i) a[i] = Asf[ty + 16 * i][kk];
            #pragma unroll
            for (int j = 0; j < 4; ++j) b[j] = Bsf[kk][tx + 16 * j];
            #pragma unroll
            for (int i = 0; i < 4; ++i)
                #pragma unroll
                for (int j = 0; j < 4; ++j) acc[i][j] += a[i] * b[j];
        }
        __syncthreads();
    }
    #pragma unroll
    for (int i = 0; i < 4; ++i) {
        int gr = row0 + ty + 16 * i;
        if (gr >= M) continue;
        #pragma unroll
        for (int j = 0; j < 4; ++j) {
            int gc = col0 + tx + 16 * j;
            if (gc >= N) continue;
            float v = acc[i][j];
            if (bias) v += bias[gc];
            C[(size_t)gr * N + gc] = v;
        }
    }
}

// =================== CSR build ===================
__global__ void zero_ints(int* __restrict__ p, int n) {
    int i = blockIdx.x * blockDim.x + threadIdx.x;
    int stride = gridDim.x * blockDim.x;
    for (; i < n; i += stride) p[i] = 0;
}

__global__ void hist_dst(const int* __restrict__ dst, int* __restrict__ counts, int E) {
    int i = blockIdx.x * blockDim.x + threadIdx.x;
    int stride = gridDim.x * blockDim.x;
    for (; i < E; i += stride) atomicAdd(&counts[dst[i]], 1);
}

__global__ void chunk_sums(const int* __restrict__ counts, int* __restrict__ csum, int N) {
    __shared__ int s[256];
    int b = blockIdx.x, t = threadIdx.x;
    int base = b * 2048 + t * 8;
    int loc = 0;
    #pragma unroll
    for (int i = 0; i < 8; ++i) {
        int gi = base + i;
        if (gi < N) loc += counts[gi];
    }
    s[t] = loc;
    __syncthreads();
    for (int off = 128; off > 0; off >>= 1) {
        if (t < off) s[t] += s[t + off];
        __syncthreads();
    }
    if (t == 0) csum[b] = s[0];
}

__global__ void scan_chunks(const int* __restrict__ csum, int* __restrict__ cbase, int NB) {
    if (blockIdx.x == 0 && threadIdx.x == 0) {
        int run = 0;
        for (int b = 0; b < NB; ++b) { cbase[b] = run; run += csum[b]; }
    }
}

__global__ void scan_final(const int* __restrict__ counts, const int* __restrict__ cbase,
                           int* __restrict__ row_start, int* __restrict__ cursor, int N) {
    __shared__ int s[256];
    int b = blockIdx.x, t = threadIdx.x;
    int base = b * 2048 + t * 8;
    int loc = 0;
    #pragma unroll
    for (int i = 0; i < 8; ++i) {
        int gi = base + i;
        if (gi < N) loc += counts[gi];
    }
    s[t] = loc;
    __syncthreads();
    for (int off = 1; off < 256; off <<= 1) {
        int v = (t >= off) ? s[t - off] : 0;
        __syncthreads();
        s[t] += v;
        __syncthreads();
    }
    int run = cbase[b] + s[t] - loc;
    for (int i = 0; i < 8; ++i) {
        int gi = base + i;
        if (gi < N) {
            row_start[gi] = run;
            cursor[gi] = run;
            run += counts[gi];
        }
    }
}

__global__ void scatter_edges(const int* __restrict__ src, const int* __restrict__ dst,
                              const float* __restrict__ w, int* __restrict__ cursor,
                              int2* __restrict__ csr, int E) {
    int i = blockIdx.x * blockDim.x + threadIdx.x;
    int stride = gridDim.x * blockDim.x;
    for (; i < E; i += stride) {
        int d = dst[i];
        int pos = atomicAdd(&cursor[d], 1);
        csr[pos] = make_int2(src[i], __float_as_int(w[i]));
    }
}

// =================== CSR SPMM (one wave per row, float4, bias+relu fused) ===================
template <int D, bool RELU>
__global__ void spmm_csr(const float* __restrict__ h, const int2* __restrict__ csr,
                         const int* __restrict__ row_start, const int* __restrict__ counts,
                         const float* __restrict__ bias, float* __restrict__ out, int N) {
    int row = blockIdx.x * 4 + (threadIdx.x >> 6);
    int lane = threadIdx.x & 63;
    if (row >= N) return;
    constexpr int VF = D / 4;                 // float4 slots per row (50 / 20)
    const bool act = lane < VF;
    int p = row_start[row], len = counts[row];
    f32x4 acc = (f32x4){0.f, 0.f, 0.f, 0.f};
    if (act) acc = ((const f32x4*)bias)[lane];
    int2 ew = (len > 0) ? csr[p] : make_int2(0, 0);
    for (int q = 0; q < len; ++q) {
        int2 cur = ew;
        if (q + 1 < len) ew = csr[p + q + 1];   // prefetch next edge meta
        float wt = __int_as_float(cur.y);
        if (act) {
            f32x4 hv = ((const f32x4*)(h + (size_t)cur.x * D))[lane];
            acc += hv * wt;
        }
    }
    if (act) {
        if (RELU) {
            #pragma unroll
            for (int c = 0; c < 4; ++c) acc[c] = acc[c] > 0.f ? acc[c] : 0.f;
        }
        ((f32x4*)(out + (size_t)row * D))[lane] = acc;
    }
}

// =================== fallback SPMM (atomic) ===================
__global__ void init_bias_kernel(float* __restrict__ agg, const float* __restrict__ bias,
                                 long long n, int D) {
    long long i = (long long)blockIdx.x * blockDim.x + threadIdx.x;
    long long stride = (long long)gridDim.x * blockDim.x;
    for (; i < n; i += stride) agg[i] = bias[(int)(i % D)];
}

template <int D>
__global__ void spmm_edges(const float* __restrict__ h, const int* __restrict__ src,
                           const int* __restrict__ dst, const float* __restrict__ w,
                           float* __restrict__ agg, int E) {
    int e = blockIdx.x * 4 + (threadIdx.x >> 6);
    int lane = threadIdx.x & 63;
    if (e >= E) return;
    int s = src[e], d = dst[e];
    float wt = w[e];
    const float* hs = h + (size_t)s * D;
    float* ad = agg + (size_t)d * D;
    for (int j = lane; j < D; j += 64) atomicAdd(&ad[j], wt * hs[j]);
}

__global__ void relu_kernel(float* __restrict__ x, long long n) {
    long long i = (long long)blockIdx.x * blockDim.x + threadIdx.x;
    long long stride = (long long)gridDim.x * blockDim.x;
    for (; i < n; i += stride) {
        float v = x[i];
        x[i] = v > 0.f ? v : 0.f;
    }
}

extern "C" void kernel_launch(void* const* d_in, const int* in_sizes, int n_in,
                              void* d_out, int out_size, void* d_ws, size_t ws_size,
                              hipStream_t stream) {
    const float* x        = (const float*)d_in[0];
    const int*   edge_src = (const int*)d_in[1];
    const int*   edge_dst = (const int*)d_in[2];
    const float* edge_w   = (const float*)d_in[3];
    const float* W1       = (const float*)d_in[4];
    const float* b1       = (const float*)d_in[5];
    const float* W2       = (const float*)d_in[6];
    const float* b2       = (const float*)d_in[7];
    const float* Wfc      = (const float*)d_in[8];
    const float* bfc      = (const float*)d_in[9];
    float* out = (float*)d_out;

    const int N = in_sizes[0] / F_IN;   // 100000
    const int E = in_sizes[1];          // 3200000
    const int NB = (N + 2047) / 2048;

    // ---- workspace layout ----
    float* h0  = (float*)d_ws;                       // N*H1
    float* agg = h0 + (size_t)N * H1;                // N*H1
    int* counts    = (int*)(agg + (size_t)N * H1);   // N
    int* row_start = counts + N;                     // N
    int* cursor    = row_start + N;                  // N
    int* csum      = cursor + N;                     // NB
    int* cbase     = csum + NB;                      // NB
    size_t csr_off = (size_t)(cbase + NB) - (size_t)d_ws;
    csr_off = (csr_off + 15) & ~(size_t)15;
    int2* csr = (int2*)((char*)d_ws + csr_off);      // E int2
    size_t boff = csr_off + (size_t)E * sizeof(int2);
    boff = (boff + 15) & ~(size_t)15;
    // GEMM1: K=1433 -> KSTEPS=45, K8P=180; COLS=208 (13 tiles)
    // GEMM2: K=200  -> KSTEPS=7,  K8P=28;  COLS=80  (5 tiles)
    // FC   : K=80   -> KSTEPS=3,  K8P=12;  COLS=16  (1 tile)
    const size_t B1n = 2ull * 180 * 208 * 8;
    const size_t B2n = 2ull * 28 * 80 * 8;
    const size_t Bfn = 2ull * 12 * 16 * 8;
    unsigned short* B1p = (unsigned short*)((char*)d_ws + boff);
    unsigned short* B2p = B1p + B1n;
    unsigned short* Bfp = B2p + B2n;
    size_t needed = boff + (B1n + B2n + Bfn) * sizeof(unsigned short);

    float* h1 = agg;
    float* h2 = h0;
    float* h3 = agg;

    const int MB = (N + 127) / 128;

    if (ws_size >= needed) {
        // ---- weight pre-convert (hi/lo bf16, fragment order) ----
        convert_B<<<(180 * 208 * 8 + 255) / 256, 256, 0, stream>>>(W1, B1p, F_IN, H1, 180, 208);
        convert_B<<<(28 * 80 * 8 + 255) / 256, 256, 0, stream>>>(W2, B2p, H1, H2, 28, 80);
        convert_B<<<(12 * 16 * 8 + 255) / 256, 256, 0, stream>>>(Wfc, Bfp, H2, NC, 12, 16);

        // ---- CSR build ----
        zero_ints<<<256, 256, 0, stream>>>(counts, N);
        hist_dst<<<2048, 256, 0, stream>>>(edge_dst, counts, E);
        chunk_sums<<<NB, 256, 0, stream>>>(counts, csum, N);
        scan_chunks<<<1, 64, 0, stream>>>(csum, cbase, NB);
        scan_final<<<NB, 256, 0, stream>>>(counts, cbase, row_start, cursor, N);
        scatter_edges<<<2048, 256, 0, stream>>>(edge_src, edge_dst, edge_w, cursor, csr, E);

        // ---- Layer 1 ----
        gemm_mfma_direct<F_IN, 45, 208, 13, false, false><<<MB, 256, 0, stream>>>(x, B1p, nullptr, h0, N, H1);
        spmm_csr<H1, true><<<(N + 3) / 4, 256, 0, stream>>>(h0, csr, row_start, counts, b1, h1, N);

        // ---- Layer 2 ----
        gemm_mfma_direct<H1, 7, 80, 5, false, true><<<MB, 256, 0, stream>>>(h1, B2p, nullptr, h2, N, H2);
        spmm_csr<H2, true><<<(N + 3) / 4, 256, 0, stream>>>(h2, csr, row_start, counts, b2, h3, N);

        // ---- FC ----
        gemm_mfma_direct<H2, 3, 16, 1, true, true><<<MB, 256, 0, stream>>>(h3, Bfp, bfc, out, N, NC);
    } else {
        // ---- fallback: fp32 everything, atomic SPMM ----
        const int tilesM = (N + 63) / 64;
        gemm_tiled<<<tilesM * 4, 256, 0, stream>>>(x, W1, nullptr, h0, N, F_IN, H1, 4);
        init_bias_kernel<<<2048, 256, 0, stream>>>(agg, b1, (long long)N * H1, H1);
        spmm_edges<H1><<<(E + 3) / 4, 256, 0, stream>>>(h0, edge_src, edge_dst, edge_w, agg, E);
        relu_kernel<<<2048, 256, 0, stream>>>(agg, (long long)N * H1);
        gemm_tiled<<<tilesM * 2, 256, 0, stream>>>(h1, W2, nullptr, h2, N, H1, H2, 2);
        init_bias_kernel<<<2048, 256, 0, stream>>>(agg, b2, (long long)N * H2, H2);
        spmm_edges<H2><<<(E + 3) / 4, 256, 0, stream>>>(h2, edge_src, edge_dst, edge_w, agg, E);
        relu_kernel<<<2048, 256, 0, stream>>>(agg, (long long)N * H2);
        gemm_tiled<<<tilesM, 256, 0, stream>>>(h3, Wfc, bfc, out, N, H2, NC, 1);
    }
}